// Round 1
// baseline (45.618 us; speedup 1.0000x reference)
//
#include <hip/hip_runtime.h>
#include <math.h>

// Problem constants (from reference)
constexpr int kHidden   = 1024;
constexpr int kSeq      = 512;
constexpr int kTokens   = 4 * 512;      // BATCH * SEQ
constexpr float kEps    = 1e-5f;

// Reduction config
constexpr int kRBlocks  = 2048;
constexpr int kRThreads = 256;

// ws layout (floats):
// [0 .. kRBlocks)              per-block mins
// [kRBlocks .. 2*kRBlocks)     per-block maxs
// [2*kRBlocks]                 scale
// [2*kRBlocks + 1]             zero_point

__global__ __launch_bounds__(kRThreads)
void minmax_partial(const float* __restrict__ w, float* __restrict__ ws, int n4) {
    const float4* __restrict__ w4 = reinterpret_cast<const float4*>(w);
    float vmin =  __builtin_inff();
    float vmax = -__builtin_inff();
    const int stride = gridDim.x * blockDim.x;
    for (int i = blockIdx.x * blockDim.x + threadIdx.x; i < n4; i += stride) {
        float4 v = w4[i];
        vmin = fminf(vmin, fminf(fminf(v.x, v.y), fminf(v.z, v.w)));
        vmax = fmaxf(vmax, fmaxf(fmaxf(v.x, v.y), fmaxf(v.z, v.w)));
    }
#pragma unroll
    for (int off = 32; off > 0; off >>= 1) {
        vmin = fminf(vmin, __shfl_down(vmin, off, 64));
        vmax = fmaxf(vmax, __shfl_down(vmax, off, 64));
    }
    __shared__ float smin[kRThreads / 64], smax[kRThreads / 64];
    const int lane = threadIdx.x & 63;
    const int wid  = threadIdx.x >> 6;
    if (lane == 0) { smin[wid] = vmin; smax[wid] = vmax; }
    __syncthreads();
    if (threadIdx.x == 0) {
        float m = smin[0], M = smax[0];
#pragma unroll
        for (int i = 1; i < kRThreads / 64; ++i) {
            m = fminf(m, smin[i]);
            M = fmaxf(M, smax[i]);
        }
        ws[blockIdx.x]            = m;
        ws[kRBlocks + blockIdx.x] = M;
    }
}

__global__ __launch_bounds__(256)
void minmax_finalize(float* __restrict__ ws) {
    float vmin =  __builtin_inff();
    float vmax = -__builtin_inff();
    for (int i = threadIdx.x; i < kRBlocks; i += 256) {
        vmin = fminf(vmin, ws[i]);
        vmax = fmaxf(vmax, ws[kRBlocks + i]);
    }
#pragma unroll
    for (int off = 32; off > 0; off >>= 1) {
        vmin = fminf(vmin, __shfl_down(vmin, off, 64));
        vmax = fmaxf(vmax, __shfl_down(vmax, off, 64));
    }
    __shared__ float smin[4], smax[4];
    const int lane = threadIdx.x & 63;
    const int wid  = threadIdx.x >> 6;
    if (lane == 0) { smin[wid] = vmin; smax[wid] = vmax; }
    __syncthreads();
    if (threadIdx.x == 0) {
        float m = fminf(fminf(smin[0], smin[1]), fminf(smin[2], smin[3]));
        float M = fmaxf(fmaxf(smax[0], smax[1]), fmaxf(smax[2], smax[3]));
        // qmin=-128, qmax=127 -> range 255
        float scale = (M - m) / 255.0f;
        float zp    = -128.0f - m / scale;
        ws[2 * kRBlocks]     = scale;
        ws[2 * kRBlocks + 1] = zp;
    }
}

// One block per token. 256 threads x 4 fp32 columns each (float4).
__global__ __launch_bounds__(256)
void embed_pe_ln(const int* __restrict__ ids,
                 const float* __restrict__ w,
                 const float* __restrict__ gamma,
                 const float* __restrict__ beta,
                 const float* __restrict__ ws,
                 float* __restrict__ out) {
    const int t   = blockIdx.x;          // token index in [0, kTokens)
    const int pos = t & (kSeq - 1);      // position within sequence
    const int tid = threadIdx.x;

    const float scale = ws[2 * kRBlocks];
    const float zp    = ws[2 * kRBlocks + 1];

    const int id = ids[t];
    const float4 v = reinterpret_cast<const float4*>(w)[(size_t)id * (kHidden / 4) + tid];
    float x[4] = {v.x, v.y, v.z, v.w};

    // fake-quant dequant: (clip(round(w/scale + zp), -128, 127) - zp) * scale
#pragma unroll
    for (int k = 0; k < 4; ++k) {
        float q = rintf(x[k] / scale + zp);   // rintf = round-half-even, matches jnp.round
        q = fminf(fmaxf(q, -128.0f), 127.0f);
        x[k] = (q - zp) * scale;
    }

    // sinusoidal PE: pe[pos, 2i] = sin(pos * exp((2i) * (-ln(10000)/1024)))
    //               pe[pos, 2i+1] = cos(...)
    // cols handled here: 4*tid .. 4*tid+3 -> div_term indices 2*tid, 2*tid+1
    const float cpe  = -0.008994473019508332f;   // float32(-ln(10000)/1024)
    const float fpos = (float)pos;
    const float a0 = fpos * expf((float)(4 * tid)     * cpe);
    const float a1 = fpos * expf((float)(4 * tid + 2) * cpe);
    float s0, c0, s1, c1;
    sincosf(a0, &s0, &c0);
    sincosf(a1, &s1, &c1);
    x[0] += s0; x[1] += c0; x[2] += s1; x[3] += c1;

    // LayerNorm over the 1024 columns of this block
    float sum = x[0] + x[1] + x[2] + x[3];
    float ssq = x[0] * x[0] + x[1] * x[1] + x[2] * x[2] + x[3] * x[3];
#pragma unroll
    for (int off = 32; off > 0; off >>= 1) {
        sum += __shfl_down(sum, off, 64);
        ssq += __shfl_down(ssq, off, 64);
    }
    __shared__ float s_sum[4], s_ssq[4], s_stats[2];
    const int lane = tid & 63;
    const int wid  = tid >> 6;
    if (lane == 0) { s_sum[wid] = sum; s_ssq[wid] = ssq; }
    __syncthreads();
    if (tid == 0) {
        float S = s_sum[0] + s_sum[1] + s_sum[2] + s_sum[3];
        float Q = s_ssq[0] + s_ssq[1] + s_ssq[2] + s_ssq[3];
        float mu  = S * (1.0f / kHidden);
        float var = Q * (1.0f / kHidden) - mu * mu;
        s_stats[0] = mu;
        s_stats[1] = rsqrtf(var + kEps);
    }
    __syncthreads();
    const float mu   = s_stats[0];
    const float rstd = s_stats[1];

    const float4 g = reinterpret_cast<const float4*>(gamma)[tid];
    const float4 b = reinterpret_cast<const float4*>(beta)[tid];
    float4 o;
    o.x = g.x * (x[0] - mu) * rstd + b.x;
    o.y = g.y * (x[1] - mu) * rstd + b.y;
    o.z = g.z * (x[2] - mu) * rstd + b.z;
    o.w = g.w * (x[3] - mu) * rstd + b.w;
    reinterpret_cast<float4*>(out)[(size_t)t * (kHidden / 4) + tid] = o;
}

extern "C" void kernel_launch(void* const* d_in, const int* in_sizes, int n_in,
                              void* d_out, int out_size, void* d_ws, size_t ws_size,
                              hipStream_t stream) {
    const int*   ids   = (const int*)d_in[0];
    const float* w     = (const float*)d_in[1];
    const float* gamma = (const float*)d_in[2];
    const float* beta  = (const float*)d_in[3];
    float* out = (float*)d_out;
    float* ws  = (float*)d_ws;

    const int n4 = in_sizes[1] / 4;   // 50257*1024/4, divisible by 4

    minmax_partial<<<kRBlocks, kRThreads, 0, stream>>>(w, ws, n4);
    minmax_finalize<<<1, 256, 0, stream>>>(ws);
    embed_pe_ln<<<kTokens, 256, 0, stream>>>(ids, w, gamma, beta, ws, out);
}

// Round 2
// 41.979 us; speedup vs baseline: 1.0867x; 1.0867x over previous
//
#include <hip/hip_runtime.h>
#include <math.h>

// Problem constants (from reference)
constexpr int kHidden   = 1024;
constexpr int kSeq      = 512;
constexpr int kTokens   = 4 * 512;      // BATCH * SEQ
constexpr float kEps    = 1e-5f;

// Reduction config
constexpr int kRBlocks  = 2048;
constexpr int kRThreads = 256;

// ws layout (floats):
// [0 .. kRBlocks)              per-block mins
// [kRBlocks .. 2*kRBlocks)     per-block maxs

__global__ __launch_bounds__(kRThreads)
void minmax_partial(const float* __restrict__ w, float* __restrict__ ws, int n4) {
    const float4* __restrict__ w4 = reinterpret_cast<const float4*>(w);
    float vmin =  __builtin_inff();
    float vmax = -__builtin_inff();
    const int stride = gridDim.x * blockDim.x;
    for (int i = blockIdx.x * blockDim.x + threadIdx.x; i < n4; i += stride) {
        float4 v = w4[i];
        vmin = fminf(vmin, fminf(fminf(v.x, v.y), fminf(v.z, v.w)));
        vmax = fmaxf(vmax, fmaxf(fmaxf(v.x, v.y), fmaxf(v.z, v.w)));
    }
#pragma unroll
    for (int off = 32; off > 0; off >>= 1) {
        vmin = fminf(vmin, __shfl_down(vmin, off, 64));
        vmax = fmaxf(vmax, __shfl_down(vmax, off, 64));
    }
    __shared__ float smin[kRThreads / 64], smax[kRThreads / 64];
    const int lane = threadIdx.x & 63;
    const int wid  = threadIdx.x >> 6;
    if (lane == 0) { smin[wid] = vmin; smax[wid] = vmax; }
    __syncthreads();
    if (threadIdx.x == 0) {
        float m = smin[0], M = smax[0];
#pragma unroll
        for (int i = 1; i < kRThreads / 64; ++i) {
            m = fminf(m, smin[i]);
            M = fmaxf(M, smax[i]);
        }
        ws[blockIdx.x]            = m;
        ws[kRBlocks + blockIdx.x] = M;
    }
}

// One block per token. 256 threads x 4 fp32 columns each (float4).
// Each block also (redundantly, deterministically) reduces the 2048+2048
// per-block min/max partials from ws to obtain scale/zero_point — this
// replaces the former 1-block finalize kernel and its serialized launch.
__global__ __launch_bounds__(256)
void embed_pe_ln(const int* __restrict__ ids,
                 const float* __restrict__ w,
                 const float* __restrict__ gamma,
                 const float* __restrict__ beta,
                 const float* __restrict__ ws,
                 float* __restrict__ out) {
    const int t   = blockIdx.x;          // token index in [0, kTokens)
    const int pos = t & (kSeq - 1);      // position within sequence
    const int tid = threadIdx.x;

    // Issue the gather load FIRST so its HBM/L3 latency hides under the
    // partial-reduce below (no dependency until the dequant step).
    const int id = ids[t];
    const float4 v = reinterpret_cast<const float4*>(w)[(size_t)id * (kHidden / 4) + tid];

    // ---- reduce ws partials -> scale, zero_point (identical in all blocks)
    const float4* __restrict__ p4 = reinterpret_cast<const float4*>(ws);
    // mins occupy float4 indices [0, 512), maxs [512, 1024)
    float vmin =  __builtin_inff();
    float vmax = -__builtin_inff();
#pragma unroll
    for (int i = 0; i < 2; ++i) {
        float4 a = p4[tid + i * 256];          // mins
        float4 b = p4[512 + tid + i * 256];    // maxs
        vmin = fminf(vmin, fminf(fminf(a.x, a.y), fminf(a.z, a.w)));
        vmax = fmaxf(vmax, fmaxf(fmaxf(b.x, b.y), fmaxf(b.z, b.w)));
    }
#pragma unroll
    for (int off = 32; off > 0; off >>= 1) {
        vmin = fminf(vmin, __shfl_down(vmin, off, 64));
        vmax = fmaxf(vmax, __shfl_down(vmax, off, 64));
    }
    __shared__ float smin[4], smax[4], s_sp[2];
    const int lane = tid & 63;
    const int wid  = tid >> 6;
    if (lane == 0) { smin[wid] = vmin; smax[wid] = vmax; }
    __syncthreads();
    if (tid == 0) {
        float m = fminf(fminf(smin[0], smin[1]), fminf(smin[2], smin[3]));
        float M = fmaxf(fmaxf(smax[0], smax[1]), fmaxf(smax[2], smax[3]));
        float scale = (M - m) / 255.0f;        // qmax-qmin = 255
        s_sp[0] = scale;
        s_sp[1] = -128.0f - m / scale;         // zero_point
    }
    __syncthreads();
    const float scale = s_sp[0];
    const float zp    = s_sp[1];

    float x[4] = {v.x, v.y, v.z, v.w};

    // fake-quant dequant: (clip(round(w/scale + zp), -128, 127) - zp) * scale
#pragma unroll
    for (int k = 0; k < 4; ++k) {
        float q = rintf(x[k] / scale + zp);   // rintf = round-half-even, matches jnp.round
        q = fminf(fmaxf(q, -128.0f), 127.0f);
        x[k] = (q - zp) * scale;
    }

    // sinusoidal PE: pe[pos, 2i] = sin(pos * exp((2i) * (-ln(10000)/1024)))
    //               pe[pos, 2i+1] = cos(...)
    // cols handled here: 4*tid .. 4*tid+3 -> div_term indices 2*tid, 2*tid+1
    const float cpe  = -0.008994473019508332f;   // float32(-ln(10000)/1024)
    const float fpos = (float)pos;
    const float a0 = fpos * expf((float)(4 * tid)     * cpe);
    const float a1 = fpos * expf((float)(4 * tid + 2) * cpe);
    float s0, c0, s1, c1;
    sincosf(a0, &s0, &c0);
    sincosf(a1, &s1, &c1);
    x[0] += s0; x[1] += c0; x[2] += s1; x[3] += c1;

    // LayerNorm over the 1024 columns of this block
    float sum = x[0] + x[1] + x[2] + x[3];
    float ssq = x[0] * x[0] + x[1] * x[1] + x[2] * x[2] + x[3] * x[3];
#pragma unroll
    for (int off = 32; off > 0; off >>= 1) {
        sum += __shfl_down(sum, off, 64);
        ssq += __shfl_down(ssq, off, 64);
    }
    __shared__ float s_sum[4], s_ssq[4], s_stats[2];
    if (lane == 0) { s_sum[wid] = sum; s_ssq[wid] = ssq; }
    __syncthreads();
    if (tid == 0) {
        float S = s_sum[0] + s_sum[1] + s_sum[2] + s_sum[3];
        float Q = s_ssq[0] + s_ssq[1] + s_ssq[2] + s_ssq[3];
        float mu  = S * (1.0f / kHidden);
        float var = Q * (1.0f / kHidden) - mu * mu;
        s_stats[0] = mu;
        s_stats[1] = rsqrtf(var + kEps);
    }
    __syncthreads();
    const float mu   = s_stats[0];
    const float rstd = s_stats[1];

    const float4 g = reinterpret_cast<const float4*>(gamma)[tid];
    const float4 b = reinterpret_cast<const float4*>(beta)[tid];
    float4 o;
    o.x = g.x * (x[0] - mu) * rstd + b.x;
    o.y = g.y * (x[1] - mu) * rstd + b.y;
    o.z = g.z * (x[2] - mu) * rstd + b.z;
    o.w = g.w * (x[3] - mu) * rstd + b.w;
    reinterpret_cast<float4*>(out)[(size_t)t * (kHidden / 4) + tid] = o;
}

extern "C" void kernel_launch(void* const* d_in, const int* in_sizes, int n_in,
                              void* d_out, int out_size, void* d_ws, size_t ws_size,
                              hipStream_t stream) {
    const int*   ids   = (const int*)d_in[0];
    const float* w     = (const float*)d_in[1];
    const float* gamma = (const float*)d_in[2];
    const float* beta  = (const float*)d_in[3];
    float* out = (float*)d_out;
    float* ws  = (float*)d_ws;

    const int n4 = in_sizes[1] / 4;   // 50257*1024/4, divisible by 4

    minmax_partial<<<kRBlocks, kRThreads, 0, stream>>>(w, ws, n4);
    embed_pe_ln<<<kTokens, 256, 0, stream>>>(ids, w, gamma, beta, ws, out);
}